// Round 4
// baseline (1568.089 us; speedup 1.0000x reference)
//
#include <hip/hip_runtime.h>

#define Nn 50000
#define Ee 500000
#define Dd 128
#define RPB 64
#define NBLK ((Nn + RPB - 1) / RPB)   // 782 blocks of 64 dest rows
#define NBUCK (NBLK * 4)              // 3128 (block,type) buckets

typedef __attribute__((ext_vector_type(8))) short bf16x8;
typedef __attribute__((ext_vector_type(4))) float f32x4;

__device__ inline unsigned short f2bf(float f) {
  unsigned u = __float_as_uint(f);
  unsigned r = u + 0x7FFFu + ((u >> 16) & 1u);
  return (unsigned short)(r >> 16);
}

// ---------------- prep: bf16 weight transposes, bias fuse, x->bf16 ----------
__global__ __launch_bounds__(256) void prep_kernel(
    const float* __restrict__ x, const float* __restrict__ W_types,
    const float* __restrict__ b_types, const float* __restrict__ W_self,
    const float* __restrict__ W_e1, const float* __restrict__ W_e2,
    const float* __restrict__ b_e2,
    unsigned short* __restrict__ xbf, unsigned short* __restrict__ WTt,
    unsigned short* __restrict__ W1T, unsigned short* __restrict__ W2T,
    unsigned short* __restrict__ WsT, float* __restrict__ biasc) {
  int i = blockIdx.x * 256 + threadIdx.x;
  if (i < 65536) {                       // W_types -> [t][n][k] bf16
    int t = i >> 14, rem = i & 16383, n = rem >> 7, k = rem & 127;
    WTt[i] = f2bf(W_types[t * 16384 + k * 128 + n]);
  } else if (i < 81920) {                // W_e1 -> [n][k]
    int j = i - 65536; int n = j >> 7, k = j & 127;
    W1T[j] = f2bf(W_e1[k * 128 + n]);
  } else if (i < 98304) {                // W_e2 -> [n][k]
    int j = i - 81920; int n = j >> 7, k = j & 127;
    W2T[j] = f2bf(W_e2[k * 128 + n]);
  } else if (i < 114688) {               // W_self -> [n][k]
    int j = i - 98304; int n = j >> 7, k = j & 127;
    WsT[j] = f2bf(W_self[k * 128 + n]);
  } else if (i < 115200) {               // biasc[t][n] = b_types + b_e2
    int j = i - 114688; int n = j & 127;
    biasc[j] = b_types[j] + b_e2[n];
  } else if (i < 115200 + Nn * Dd) {     // x -> bf16
    int j = i - 115200;
    xbf[j] = f2bf(x[j]);
  }
}

// -------- counting sort of edges by (dest_row>>6, type) ---------------------
__global__ __launch_bounds__(256) void bhist_kernel(const int* __restrict__ eidx,
                                                    const int* __restrict__ et,
                                                    int* __restrict__ cnt) {
  for (int e = blockIdx.x * 256 + threadIdx.x; e < Ee; e += gridDim.x * 256)
    atomicAdd(&cnt[(eidx[e] >> 6) * 4 + et[e]], 1);
}

__global__ __launch_bounds__(256) void scan1_kernel(const int* __restrict__ cnt,
                                                    int* __restrict__ blocksum,
                                                    int n) {
  __shared__ int sh[256];
  int idx = blockIdx.x * 256 + threadIdx.x;
  sh[threadIdx.x] = idx < n ? cnt[idx] : 0;
  __syncthreads();
  for (int off = 128; off > 0; off >>= 1) {
    if (threadIdx.x < off) sh[threadIdx.x] += sh[threadIdx.x + off];
    __syncthreads();
  }
  if (threadIdx.x == 0) blocksum[blockIdx.x] = sh[0];
}

__global__ __launch_bounds__(256) void scan2_kernel(const int* __restrict__ blocksum,
                                                    int* __restrict__ blockoff,
                                                    int nblk) {
  __shared__ int sh[256];
  int t = threadIdx.x;
  int v = t < nblk ? blocksum[t] : 0;
  sh[t] = v;
  __syncthreads();
  for (int off = 1; off < 256; off <<= 1) {
    int add = t >= off ? sh[t - off] : 0;
    __syncthreads();
    sh[t] += add;
    __syncthreads();
  }
  if (t < nblk) blockoff[t] = sh[t] - v;  // exclusive; GUARDED (r3 bug: t<256
                                          // writes trampled wq -> zero output)
}

__global__ __launch_bounds__(256) void scan3_kernel(const int* __restrict__ cnt,
                                                    const int* __restrict__ blockoff,
                                                    int* __restrict__ bstart,
                                                    int* __restrict__ bcur, int n) {
  __shared__ int sh[256];
  int t = threadIdx.x;
  int idx = blockIdx.x * 256 + t;
  int v = idx < n ? cnt[idx] : 0;
  sh[t] = v;
  __syncthreads();
  for (int off = 1; off < 256; off <<= 1) {
    int add = t >= off ? sh[t - off] : 0;
    __syncthreads();
    sh[t] += add;
    __syncthreads();
  }
  if (idx < n) {
    int s = sh[t] - v + blockoff[blockIdx.x];
    bstart[idx] = s;
    bcur[idx] = s;
  }
}

__global__ __launch_bounds__(256) void bscatter_kernel(const int* __restrict__ eidx,
                                                       const int* __restrict__ et,
                                                       int* __restrict__ bcur,
                                                       int* __restrict__ sorted) {
  for (int e = blockIdx.x * 256 + threadIdx.x; e < Ee; e += gridDim.x * 256) {
    int key = (eidx[e] >> 6) * 4 + et[e];
    int pos = atomicAdd(&bcur[key], 1);
    sorted[pos] = e;
  }
}

// ---- fused: edges (3 GEMMs) -> LDS accum -> self GEMM -> LN -> ReLU -> out -
// Each work item = 64 dest rows owned EXCLUSIVELY by one block (bucket sort
// guarantees all edges for those rows are contiguous). Zero global atomics.
// mfma_f32_16x16x32_bf16 layouts (guide-verified):
//   A: lane holds A[m=lane&15][k=quad*8+j] ; B: B[k=quad*8+j][n=lane&15]
//   C/D: col=lane&15, row=quad*4+reg
__global__ __launch_bounds__(256) void fused_kernel(
    const int* __restrict__ edge_index, const int* __restrict__ etype,
    const float* __restrict__ ef, const unsigned short* __restrict__ xbf,
    const unsigned short* __restrict__ WTt, const unsigned short* __restrict__ W1T,
    const unsigned short* __restrict__ W2T, const unsigned short* __restrict__ WsT,
    const float* __restrict__ biasc, const float* __restrict__ b_e1,
    const float* __restrict__ b_self, const float* __restrict__ ln_g,
    const float* __restrict__ ln_b, const int* __restrict__ bstart,
    const int* __restrict__ rowsorted, int* __restrict__ wq,
    float* __restrict__ out) {
  __shared__ unsigned short Ax[64][136];   // +16B pad: 2-way banks only (free)
  __shared__ unsigned short Ae[64][136];
  __shared__ float Acc[64][132];           // per-dest-row fp32 accumulator
  __shared__ float Bc[4][128];             // biasc staged
  __shared__ int mdl[64];
  __shared__ int mtype[64];
  __shared__ int tmask_s;
  __shared__ int curb_s;
  __shared__ float P1[64][4], P2[64][4], MU[64], RS[64];

  const int tid = threadIdx.x;
  const int w = tid >> 6, l = tid & 63, quad = l >> 4, lm = l & 15;
  const int mr = w * 16 + lm;

  // per-lane constants (same every tile)
  float be1r[8], bsr[8];
#pragma unroll
  for (int c = 0; c < 8; ++c) {
    be1r[c] = b_e1[c * 16 + lm];
    bsr[c] = b_self[c * 16 + lm];
  }
  ((float*)Bc)[tid] = biasc[tid];
  ((float*)Bc)[tid + 256] = biasc[tid + 256];

  for (;;) {
    if (tid == 0) curb_s = atomicAdd(wq, 1);
    __syncthreads();
    const int b = curb_s;
    if (b >= NBLK) break;
    const int r0 = b * RPB;
    const int e0 = bstart[b * 4];
    const int e1 = (b == NBLK - 1) ? Ee : bstart[(b + 1) * 4];

    for (int i = tid; i < 64 * 132; i += 256) ((float*)Acc)[i] = 0.f;

    for (int t0 = e0; t0 < e1; t0 += 64) {
      __syncthreads();  // prior tile's Ax/Ae/meta reads complete
      if (w == 0) {     // wave 0: meta + type mask via ballot (no atomics)
        int i = t0 + l;
        int dl = -1, t = -1;
        if (i < e1) {
          int e = rowsorted[i];
          dl = edge_index[e] - r0;   // in [0,64) by bucket-sort construction
          t = etype[e];
        }
        mdl[l] = dl;
        mtype[l] = t;
        unsigned long long b0 = __ballot(t == 0), b1 = __ballot(t == 1);
        unsigned long long b2 = __ballot(t == 2), b3 = __ballot(t == 3);
        if (l == 0)
          tmask_s = (b0 ? 1 : 0) | (b1 ? 2 : 0) | (b2 ? 4 : 0) | (b3 ? 8 : 0);
      }
      // stage A tiles: 4 threads per edge row, 32 cols each
      {
        const int r = tid >> 2;
        const int c0 = (tid & 3) * 32;
        int i = t0 + r;
        if (i < e1) {
          int e = rowsorted[i];
          int cn = edge_index[Ee + e];  // source node
          const uint4* xs = (const uint4*)(xbf + cn * Dd + c0);
          uint4* xd = (uint4*)&Ax[r][c0];
          xd[0] = xs[0]; xd[1] = xs[1]; xd[2] = xs[2]; xd[3] = xs[3];
          const float4* es = (const float4*)(ef + (long long)e * Dd + c0);
#pragma unroll
          for (int j = 0; j < 8; ++j) {
            float4 v = es[j];
            ushort4 p;
            p.x = f2bf(v.x); p.y = f2bf(v.y); p.z = f2bf(v.z); p.w = f2bf(v.w);
            *(ushort4*)&Ae[r][c0 + j * 4] = p;
          }
        } else {
          uint4 z = {0, 0, 0, 0};
          uint4* xd = (uint4*)&Ax[r][c0]; xd[0] = z; xd[1] = z; xd[2] = z; xd[3] = z;
          uint4* ed = (uint4*)&Ae[r][c0]; ed[0] = z; ed[1] = z; ed[2] = z; ed[3] = z;
        }
      }
      __syncthreads();

      f32x4 msg[8];
#pragma unroll
      for (int c = 0; c < 8; ++c) msg[c] = (f32x4){0.f, 0.f, 0.f, 0.f};

      const int myt = mtype[mr];
      const int tmask = tmask_s;

      // GEMM1: typed transform; type sub-sort makes most tiles 1 pass
      for (int t = 0; t < 4; ++t) {
        if (!(tmask & (1 << t))) continue;
        const unsigned short* Wt = WTt + t * Dd * Dd;
#pragma unroll
        for (int ks = 0; ks < 4; ++ks) {
          bf16x8 a = *(const bf16x8*)&Ax[mr][ks * 32 + quad * 8];
          if (myt != t) a = (bf16x8){0, 0, 0, 0, 0, 0, 0, 0};
#pragma unroll
          for (int c = 0; c < 8; ++c) {
            bf16x8 bb = *(const bf16x8*)(Wt + (c * 16 + lm) * Dd + ks * 32 + quad * 8);
            msg[c] = __builtin_amdgcn_mfma_f32_16x16x32_bf16(a, bb, msg[c], 0, 0, 0);
          }
        }
      }

      // GEMM2: H = ef @ W1
      f32x4 h[8];
#pragma unroll
      for (int c = 0; c < 8; ++c) h[c] = (f32x4){0.f, 0.f, 0.f, 0.f};
#pragma unroll
      for (int ks = 0; ks < 4; ++ks) {
        bf16x8 a = *(const bf16x8*)&Ae[mr][ks * 32 + quad * 8];
#pragma unroll
        for (int c = 0; c < 8; ++c) {
          bf16x8 bb = *(const bf16x8*)(W1T + (c * 16 + lm) * Dd + ks * 32 + quad * 8);
          h[c] = __builtin_amdgcn_mfma_f32_16x16x32_bf16(a, bb, h[c], 0, 0, 0);
        }
      }
      // +b1, relu, write back into own strip of Ae in A-layout
#pragma unroll
      for (int c = 0; c < 8; ++c) {
        int n = c * 16 + lm;
#pragma unroll
        for (int r4 = 0; r4 < 4; ++r4) {
          float v = h[c][r4] + be1r[c];
          v = v > 0.f ? v : 0.f;
          Ae[w * 16 + quad * 4 + r4][n] = f2bf(v);
        }
      }
      __syncthreads();

      // GEMM3: msg += relu(H) @ W2
#pragma unroll
      for (int ks = 0; ks < 4; ++ks) {
        bf16x8 a = *(const bf16x8*)&Ae[mr][ks * 32 + quad * 8];
#pragma unroll
        for (int c = 0; c < 8; ++c) {
          bf16x8 bb = *(const bf16x8*)(W2T + (c * 16 + lm) * Dd + ks * 32 + quad * 8);
          msg[c] = __builtin_amdgcn_mfma_f32_16x16x32_bf16(a, bb, msg[c], 0, 0, 0);
        }
      }

      // scatter into LDS accumulator (+ per-edge bias), CU-local ds_add
#pragma unroll
      for (int r4 = 0; r4 < 4; ++r4) {
        int m = w * 16 + quad * 4 + r4;
        int dl = mdl[m];
        if (dl < 0) continue;
        int t = mtype[m];
#pragma unroll
        for (int c = 0; c < 8; ++c) {
          int n = c * 16 + lm;
          atomicAdd(&Acc[dl][n], msg[c][r4] + Bc[t][n]);
        }
      }
    }
    __syncthreads();  // all ds_adds visible

    // self transform on the block's own dest rows (reuse Ax)
    {
      const int r = tid >> 2, c0 = (tid & 3) * 32;
      int row = r0 + r;
      if (row < Nn) {
        const uint4* xs = (const uint4*)(xbf + row * Dd + c0);
        uint4* xd = (uint4*)&Ax[r][c0];
        xd[0] = xs[0]; xd[1] = xs[1]; xd[2] = xs[2]; xd[3] = xs[3];
      } else {
        uint4 z = {0, 0, 0, 0};
        uint4* xd = (uint4*)&Ax[r][c0];
        xd[0] = z; xd[1] = z; xd[2] = z; xd[3] = z;
      }
    }
    __syncthreads();
    f32x4 sacc[8];
#pragma unroll
    for (int c = 0; c < 8; ++c) sacc[c] = (f32x4){0.f, 0.f, 0.f, 0.f};
#pragma unroll
    for (int ks = 0; ks < 4; ++ks) {
      bf16x8 a = *(const bf16x8*)&Ax[mr][ks * 32 + quad * 8];
#pragma unroll
      for (int c = 0; c < 8; ++c) {
        bf16x8 bb = *(const bf16x8*)(WsT + (c * 16 + lm) * Dd + ks * 32 + quad * 8);
        sacc[c] = __builtin_amdgcn_mfma_f32_16x16x32_bf16(a, bb, sacc[c], 0, 0, 0);
      }
    }
    // combine into Acc (each (m,n) touched by exactly one lane)
#pragma unroll
    for (int c = 0; c < 8; ++c) {
      int n = c * 16 + lm;
#pragma unroll
      for (int r4 = 0; r4 < 4; ++r4) {
        int m = w * 16 + quad * 4 + r4;
        Acc[m][n] = sacc[c][r4] + bsr[c] + Acc[m][n];
      }
    }
    __syncthreads();
    // LayerNorm partials: 4 threads per row
    {
      const int r = tid >> 2, sgi = tid & 3, c0 = sgi * 32;
      float s1 = 0.f, s2 = 0.f;
#pragma unroll
      for (int j = 0; j < 32; ++j) { float v = Acc[r][c0 + j]; s1 += v; s2 += v * v; }
      P1[r][sgi] = s1; P2[r][sgi] = s2;
    }
    __syncthreads();
    if (tid < 64) {
      float s1 = P1[tid][0] + P1[tid][1] + P1[tid][2] + P1[tid][3];
      float s2 = P2[tid][0] + P2[tid][1] + P2[tid][2] + P2[tid][3];
      float mu = s1 * (1.f / 128.f);
      float var = s2 * (1.f / 128.f) - mu * mu;
      MU[tid] = mu;
      RS[tid] = rsqrtf(var + 1e-5f);
    }
    __syncthreads();
    {
      const int r = tid >> 2, c0 = (tid & 3) * 32;
      int row = r0 + r;
      if (row < Nn) {
        float mu = MU[r], rs = RS[r];
        float* op = out + (long long)row * Dd + c0;
#pragma unroll
        for (int j = 0; j < 32; ++j) {
          float v = (Acc[r][c0 + j] - mu) * rs * ln_g[c0 + j] + ln_b[c0 + j];
          op[j] = v > 0.f ? v : 0.f;
        }
      }
    }
  }
}

// ---------------- launch ----------------------------------------------------
extern "C" void kernel_launch(void* const* d_in, const int* in_sizes, int n_in,
                              void* d_out, int out_size, void* d_ws, size_t ws_size,
                              hipStream_t stream) {
  (void)in_sizes; (void)n_in; (void)out_size; (void)ws_size;
  const float* x       = (const float*)d_in[0];
  const int*   eidx    = (const int*)d_in[1];
  const int*   etype   = (const int*)d_in[2];
  const float* ef      = (const float*)d_in[3];
  const float* W_types = (const float*)d_in[4];
  const float* b_types = (const float*)d_in[5];
  const float* W_self  = (const float*)d_in[6];
  const float* b_self  = (const float*)d_in[7];
  const float* W_e1    = (const float*)d_in[8];
  const float* b_e1    = (const float*)d_in[9];
  const float* W_e2    = (const float*)d_in[10];
  const float* b_e2    = (const float*)d_in[11];
  const float* ln_g    = (const float*)d_in[12];
  const float* ln_b    = (const float*)d_in[13];
  float* out = (float*)d_out;

  char* ws = (char*)d_ws;
  // layout — every region padded well past its true size (r3 lesson)
  int*            cnt      = (int*)ws;                    // 12,512 B used / 16,384 resv
  int*            bstart   = (int*)(ws + 16384);          // 12,512 / 16,384
  int*            bcur     = (int*)(ws + 32768);          // 12,512 / 16,384
  int*            blocksum = (int*)(ws + 49152);          // 1,024 (256 ints, full)
  int*            blockoff = (int*)(ws + 50176);          // 1,024 (256 ints, full)
  int*            wq       = (int*)(ws + 51200);          // 4
  int*            rowsorted= (int*)(ws + 53248);          // 2,000,000 B
  unsigned short* xbf      = (unsigned short*)(ws + 2053248);   // 12,800,000 B
  unsigned short* WTt      = (unsigned short*)(ws + 14853248);  // 131,072 B
  unsigned short* W1T      = WTt + 4 * 128 * 128;
  unsigned short* W2T      = W1T + 128 * 128;
  unsigned short* WsT      = W2T + 128 * 128;
  float*          biasc    = (float*)(WsT + 128 * 128);   // 2,048 B

  const int nblk2 = (NBUCK + 255) / 256;  // 13

  hipMemsetAsync(ws, 0, 53248, stream);  // cnt + sums + wq

  prep_kernel<<<25450, 256, 0, stream>>>(x, W_types, b_types, W_self, W_e1, W_e2,
                                         b_e2, xbf, WTt, W1T, W2T, WsT, biasc);
  bhist_kernel<<<512, 256, 0, stream>>>(eidx, etype, cnt);
  scan1_kernel<<<nblk2, 256, 0, stream>>>(cnt, blocksum, NBUCK);
  scan2_kernel<<<1, 256, 0, stream>>>(blocksum, blockoff, nblk2);
  scan3_kernel<<<nblk2, 256, 0, stream>>>(cnt, blockoff, bstart, bcur, NBUCK);
  bscatter_kernel<<<512, 256, 0, stream>>>(eidx, etype, bcur, rowsorted);
  fused_kernel<<<512, 256, 0, stream>>>(eidx, etype, ef, xbf, WTt, W1T, W2T, WsT,
                                        biasc, b_e1, b_self, ln_g, ln_b,
                                        bstart, rowsorted, wq, out);
}

// Round 5
// 1566.159 us; speedup vs baseline: 1.0012x; 1.0012x over previous
//
#include <hip/hip_runtime.h>

#define Nn 50000
#define Ee 500000
#define Dd 128
#define RPB 32
#define NBLK ((Nn + RPB - 1) / RPB)   // 1563 blocks of 32 dest rows
#define NBUCK (NBLK * 4)              // 6252 (block,type) buckets

typedef __attribute__((ext_vector_type(8))) short bf16x8;
typedef __attribute__((ext_vector_type(4))) float f32x4;

__device__ inline unsigned short f2bf(float f) {
  unsigned u = __float_as_uint(f);
  unsigned r = u + 0x7FFFu + ((u >> 16) & 1u);
  return (unsigned short)(r >> 16);
}

__device__ inline bf16x8 pk8(float4 a, float4 b) {
  bf16x8 r;
  r[0] = (short)f2bf(a.x); r[1] = (short)f2bf(a.y);
  r[2] = (short)f2bf(a.z); r[3] = (short)f2bf(a.w);
  r[4] = (short)f2bf(b.x); r[5] = (short)f2bf(b.y);
  r[6] = (short)f2bf(b.z); r[7] = (short)f2bf(b.w);
  return r;
}

// ---------------- prep: bf16 weight transposes, bias fuse, x->bf16 ----------
__global__ __launch_bounds__(256) void prep_kernel(
    const float* __restrict__ x, const float* __restrict__ W_types,
    const float* __restrict__ b_types, const float* __restrict__ W_self,
    const float* __restrict__ W_e1, const float* __restrict__ W_e2,
    const float* __restrict__ b_e2,
    unsigned short* __restrict__ xbf, unsigned short* __restrict__ WTt,
    unsigned short* __restrict__ W1T, unsigned short* __restrict__ W2T,
    unsigned short* __restrict__ WsT, float* __restrict__ biasc) {
  int i = blockIdx.x * 256 + threadIdx.x;
  if (i < 65536) {                       // W_types -> [t][n][k] bf16
    int t = i >> 14, rem = i & 16383, n = rem >> 7, k = rem & 127;
    WTt[i] = f2bf(W_types[t * 16384 + k * 128 + n]);
  } else if (i < 81920) {                // W_e1 -> [n][k]
    int j = i - 65536; int n = j >> 7, k = j & 127;
    W1T[j] = f2bf(W_e1[k * 128 + n]);
  } else if (i < 98304) {                // W_e2 -> [n][k]
    int j = i - 81920; int n = j >> 7, k = j & 127;
    W2T[j] = f2bf(W_e2[k * 128 + n]);
  } else if (i < 114688) {               // W_self -> [n][k]
    int j = i - 98304; int n = j >> 7, k = j & 127;
    WsT[j] = f2bf(W_self[k * 128 + n]);
  } else if (i < 115200) {               // biasc[t][n] = b_types + b_e2
    int j = i - 114688; int n = j & 127;
    biasc[j] = b_types[j] + b_e2[n];
  } else if (i < 115200 + Nn * Dd) {     // x -> bf16
    int j = i - 115200;
    xbf[j] = f2bf(x[j]);
  }
}

// -------- counting sort of edges by (dest_row>>5, type) ---------------------
__global__ __launch_bounds__(256) void bhist_kernel(const int* __restrict__ eidx,
                                                    const int* __restrict__ et,
                                                    int* __restrict__ cnt) {
  for (int e = blockIdx.x * 256 + threadIdx.x; e < Ee; e += gridDim.x * 256)
    atomicAdd(&cnt[(eidx[e] >> 5) * 4 + et[e]], 1);
}

__global__ __launch_bounds__(256) void scan1_kernel(const int* __restrict__ cnt,
                                                    int* __restrict__ blocksum,
                                                    int n) {
  __shared__ int sh[256];
  int idx = blockIdx.x * 256 + threadIdx.x;
  sh[threadIdx.x] = idx < n ? cnt[idx] : 0;
  __syncthreads();
  for (int off = 128; off > 0; off >>= 1) {
    if (threadIdx.x < off) sh[threadIdx.x] += sh[threadIdx.x + off];
    __syncthreads();
  }
  if (threadIdx.x == 0) blocksum[blockIdx.x] = sh[0];
}

__global__ __launch_bounds__(256) void scan2_kernel(const int* __restrict__ blocksum,
                                                    int* __restrict__ blockoff,
                                                    int nblk) {
  __shared__ int sh[256];
  int t = threadIdx.x;
  int v = t < nblk ? blocksum[t] : 0;
  sh[t] = v;
  __syncthreads();
  for (int off = 1; off < 256; off <<= 1) {
    int add = t >= off ? sh[t - off] : 0;
    __syncthreads();
    sh[t] += add;
    __syncthreads();
  }
  if (t < nblk) blockoff[t] = sh[t] - v;  // exclusive; guarded (r3 lesson)
}

__global__ __launch_bounds__(256) void scan3_kernel(const int* __restrict__ cnt,
                                                    const int* __restrict__ blockoff,
                                                    int* __restrict__ bstart,
                                                    int* __restrict__ bcur, int n) {
  __shared__ int sh[256];
  int t = threadIdx.x;
  int idx = blockIdx.x * 256 + t;
  int v = idx < n ? cnt[idx] : 0;
  sh[t] = v;
  __syncthreads();
  for (int off = 1; off < 256; off <<= 1) {
    int add = t >= off ? sh[t - off] : 0;
    __syncthreads();
    sh[t] += add;
    __syncthreads();
  }
  if (idx < n) {
    int s = sh[t] - v + blockoff[blockIdx.x];
    bstart[idx] = s;
    bcur[idx] = s;
  }
}

__global__ __launch_bounds__(256) void bscatter_kernel(const int* __restrict__ eidx,
                                                       const int* __restrict__ et,
                                                       int* __restrict__ bcur,
                                                       int* __restrict__ sorted) {
  for (int e = blockIdx.x * 256 + threadIdx.x; e < Ee; e += gridDim.x * 256) {
    int key = (eidx[e] >> 5) * 4 + et[e];
    int pos = atomicAdd(&bcur[key], 1);
    sorted[pos] = e;
  }
}

// ---- fused, TRANSPOSED GEMMs: weights = A-operand, edge data = B-operand ---
// D[m=feature][n=edge]: A-frag lane(q,lm) = W*T[(c*16+lm)*128 + ks*32+q*8..+7]
// (row-contiguous 16B), B-frag = edge row [src*128 + ks*32+q*8..+7] direct
// from global (64B coalesced chunks). C/D: lane(q,lm) holds edge lm, features
// 16c+4q+r. H round-trips through wave-private Ht[16 edges][128 features]
// (8B writes / 16B reads, no barrier: per-wave DS is in-order). Edge loop has
// ZERO barriers; only Acc (ds_add_f32) and Tcnt are cross-wave.
__global__ __launch_bounds__(256, 4) void fused_kernel(
    const int* __restrict__ edge_index, const int* __restrict__ etype,
    const float* __restrict__ ef, const unsigned short* __restrict__ xbf,
    const unsigned short* __restrict__ WTt, const unsigned short* __restrict__ W1T,
    const unsigned short* __restrict__ W2T, const unsigned short* __restrict__ WsT,
    const float* __restrict__ biasc, const float* __restrict__ b_e1,
    const float* __restrict__ b_self, const float* __restrict__ ln_g,
    const float* __restrict__ ln_b, const int* __restrict__ bstart,
    const int* __restrict__ rowsorted, int* __restrict__ wq,
    float* __restrict__ out) {
  __shared__ unsigned short Ht[4][16][136];  // per-wave H^T scratch (17.4 KB)
  __shared__ float Acc[32][132];             // dest-row accumulator (16.9 KB)
  __shared__ int Tcnt[32][4];                // per-(row,type) edge counts
  __shared__ float BcP[4][128];              // biasc permuted [t][q*32+c*4+r]
  __shared__ float B1p[128];                 // b_e1 permuted
  __shared__ float Bsp[128];                 // b_self permuted
  __shared__ int mew[4][16], mdlw[4][16], mtyw[4][16];
  __shared__ float P1[32][4], P2[32][4], MU[32], RS[32];
  __shared__ int curb_s;

  const int tid = threadIdx.x;
  const int w = tid >> 6, l = tid & 63, q = l >> 4, lm = l & 15;

  // permuted bias staging: index = q*32 + c*4 + r  <->  feature 16c+4q+r
  if (tid < 128) {
    int pq = tid >> 5, pc = (tid >> 2) & 7, pr = tid & 3;
    int f = pc * 16 + pq * 4 + pr;
    B1p[tid] = b_e1[f];
    Bsp[tid] = b_self[f];
#pragma unroll
    for (int t = 0; t < 4; ++t) BcP[t][tid] = biasc[t * 128 + f];
  }

  for (;;) {
    if (tid == 0) curb_s = atomicAdd(wq, 1);
    __syncthreads();  // also orders prior epilogue reads vs re-zero below
    const int b = curb_s;
    if (b >= NBLK) break;
    const int r0 = b * RPB;
    const int e0 = bstart[b * 4];
    const int e1 = (b == NBLK - 1) ? Ee : bstart[(b + 1) * 4];

    for (int i = tid; i < 32 * 132; i += 256) ((float*)Acc)[i] = 0.f;
    if (tid < 128) ((int*)Tcnt)[tid] = 0;
    __syncthreads();

    // -------- per-wave independent 16-edge groups (no barriers) ------------
    for (int i0 = e0 + w * 16; i0 < e1; i0 += 64) {
      int tl = -1;
      if (l < 16) {
        int idx = i0 + l;
        int e = 0, dl = -1;
        if (idx < e1) {
          e = rowsorted[idx];
          dl = edge_index[e] - r0;  // in [0,32) by bucket construction
          tl = etype[e];
        }
        mew[w][l] = e; mdlw[w][l] = dl; mtyw[w][l] = tl;
        if (dl >= 0) atomicAdd(&Tcnt[dl][tl], 1);
      }
      int tmask = 0;
      if (__ballot(tl == 0)) tmask |= 1;
      if (__ballot(tl == 1)) tmask |= 2;
      if (__ballot(tl == 2)) tmask |= 4;
      if (__ballot(tl == 3)) tmask |= 8;

      const int e_lm = mew[w][lm];
      const int myt = mtyw[w][lm];
      const int dl_lm = mdlw[w][lm];
      const int src = edge_index[Ee + e_lm];

      f32x4 acc8[8];

      // GEMM2': H^T = W1^T @ ef^T, acc init = b_e1 (feature-indexed)
#pragma unroll
      for (int c = 0; c < 8; ++c) acc8[c] = *(const f32x4*)&B1p[q * 32 + c * 4];
      {
        const float* efp = ef + (long long)e_lm * Dd + q * 8;
#pragma unroll
        for (int ks = 0; ks < 4; ++ks) {
          float4 va = *(const float4*)(efp + ks * 32);
          float4 vb = *(const float4*)(efp + ks * 32 + 4);
          bf16x8 bfr = pk8(va, vb);
#pragma unroll
          for (int c = 0; c < 8; ++c) {
            bf16x8 a = *(const bf16x8*)(W1T + (c * 16 + lm) * Dd + ks * 32 + q * 8);
            acc8[c] = __builtin_amdgcn_mfma_f32_16x16x32_bf16(a, bfr, acc8[c], 0, 0, 0);
          }
        }
      }
      // relu + pack -> Ht (wave-private; 8B writes, cols 16c+4q..+3 of row lm)
#pragma unroll
      for (int c = 0; c < 8; ++c) {
        ushort4 p;
        float v0 = acc8[c][0] > 0.f ? acc8[c][0] : 0.f;
        float v1 = acc8[c][1] > 0.f ? acc8[c][1] : 0.f;
        float v2 = acc8[c][2] > 0.f ? acc8[c][2] : 0.f;
        float v3 = acc8[c][3] > 0.f ? acc8[c][3] : 0.f;
        p.x = f2bf(v0); p.y = f2bf(v1); p.z = f2bf(v2); p.w = f2bf(v3);
        *(ushort4*)&Ht[w][lm][c * 16 + q * 4] = p;
      }

      // GEMM3'': msg^T = W2^T @ H^T  (B-frag = 16B read of Ht row lm)
#pragma unroll
      for (int c = 0; c < 8; ++c) acc8[c] = (f32x4){0.f, 0.f, 0.f, 0.f};
#pragma unroll
      for (int ks = 0; ks < 4; ++ks) {
        bf16x8 bh = *(const bf16x8*)&Ht[w][lm][ks * 32 + q * 8];
#pragma unroll
        for (int c = 0; c < 8; ++c) {
          bf16x8 a = *(const bf16x8*)(W2T + (c * 16 + lm) * Dd + ks * 32 + q * 8);
          acc8[c] = __builtin_amdgcn_mfma_f32_16x16x32_bf16(a, bh, acc8[c], 0, 0, 0);
        }
      }

      // GEMM1: msg^T += Wt^T @ x_col^T, per-lane (=per-edge) type mask
      {
        const unsigned short* xrow = xbf + (long long)src * Dd + q * 8;
        for (int t = 0; t < 4; ++t) {
          if (!(tmask & (1 << t))) continue;
          const bool on = (myt == t);
#pragma unroll
          for (int ks = 0; ks < 4; ++ks) {
            bf16x8 bx = on ? *(const bf16x8*)(xrow + ks * 32)
                           : (bf16x8){0, 0, 0, 0, 0, 0, 0, 0};
#pragma unroll
            for (int c = 0; c < 8; ++c) {
              bf16x8 a = *(const bf16x8*)(WTt + t * 16384 + (c * 16 + lm) * Dd +
                                          ks * 32 + q * 8);
              acc8[c] = __builtin_amdgcn_mfma_f32_16x16x32_bf16(a, bx, acc8[c], 0, 0, 0);
            }
          }
        }
      }

      // accumulate edge lm into its dest row (type bias handled via Tcnt)
      if (dl_lm >= 0) {
#pragma unroll
        for (int c = 0; c < 8; ++c)
#pragma unroll
          for (int r = 0; r < 4; ++r)
            atomicAdd(&Acc[dl_lm][c * 16 + q * 4 + r], acc8[c][r]);
      }
    }
    __syncthreads();  // all waves' ds_adds + Tcnt done

    // -------- self transform (transposed), + type-bias, into Acc ----------
    {
      const int nh = (w & 1) * 16, ch = (w >> 1) * 4;
      const int node = r0 + nh + lm;
      const int nclamp = node < Nn ? node : 0;
      const unsigned short* xrow = xbf + (long long)nclamp * Dd + q * 8;
      f32x4 sa[4];
#pragma unroll
      for (int c4 = 0; c4 < 4; ++c4)
        sa[c4] = *(const f32x4*)&Bsp[q * 32 + (ch + c4) * 4];
#pragma unroll
      for (int ks = 0; ks < 4; ++ks) {
        bf16x8 bx = *(const bf16x8*)(xrow + ks * 32);
#pragma unroll
        for (int c4 = 0; c4 < 4; ++c4) {
          bf16x8 a = *(const bf16x8*)(WsT + ((ch + c4) * 16 + lm) * Dd + ks * 32 + q * 8);
          sa[c4] = __builtin_amdgcn_mfma_f32_16x16x32_bf16(a, bx, sa[c4], 0, 0, 0);
        }
      }
      const int rl = nh + lm;
      int4 tc = *(const int4*)&Tcnt[rl][0];
      float f0 = (float)tc.x, f1 = (float)tc.y, f2 = (float)tc.z, f3 = (float)tc.w;
#pragma unroll
      for (int c4 = 0; c4 < 4; ++c4) {
        int off = q * 32 + (ch + c4) * 4;
        f32x4 bias = f0 * (*(const f32x4*)&BcP[0][off]) +
                     f1 * (*(const f32x4*)&BcP[1][off]) +
                     f2 * (*(const f32x4*)&BcP[2][off]) +
                     f3 * (*(const f32x4*)&BcP[3][off]);
        f32x4* ap = (f32x4*)&Acc[rl][(ch + c4) * 16 + q * 4];
        *ap = *ap + sa[c4] + bias;  // disjoint (row,col) per lane across waves
      }
    }
    __syncthreads();

    // -------- LayerNorm + ReLU + store ------------------------------------
    if (tid < 128) {
      const int r = tid >> 2, sgi = tid & 3, c0 = sgi * 32;
      float s1 = 0.f, s2 = 0.f;
#pragma unroll
      for (int j = 0; j < 32; j += 4) {
        f32x4 v = *(const f32x4*)&Acc[r][c0 + j];
        s1 += v[0] + v[1] + v[2] + v[3];
        s2 += v[0] * v[0] + v[1] * v[1] + v[2] * v[2] + v[3] * v[3];
      }
      P1[r][sgi] = s1; P2[r][sgi] = s2;
    }
    __syncthreads();
    if (tid < 32) {
      float s1 = P1[tid][0] + P1[tid][1] + P1[tid][2] + P1[tid][3];
      float s2 = P2[tid][0] + P2[tid][1] + P2[tid][2] + P2[tid][3];
      float mu = s1 * (1.f / 128.f);
      float var = s2 * (1.f / 128.f) - mu * mu;
      MU[tid] = mu;
      RS[tid] = rsqrtf(var + 1e-5f);
    }
    __syncthreads();
    if (tid < 128) {
      const int r = tid >> 2, c0 = (tid & 3) * 32;
      int row = r0 + r;
      if (row < Nn) {
        float mu = MU[r], rs = RS[r];
        float* op = out + (long long)row * Dd + c0;
#pragma unroll
        for (int j = 0; j < 32; j += 4) {
          float4 g = *(const float4*)&ln_g[c0 + j];
          float4 bb = *(const float4*)&ln_b[c0 + j];
          f32x4 v = *(const f32x4*)&Acc[r][c0 + j];
          float4 o;
          o.x = (v[0] - mu) * rs * g.x + bb.x; o.x = o.x > 0.f ? o.x : 0.f;
          o.y = (v[1] - mu) * rs * g.y + bb.y; o.y = o.y > 0.f ? o.y : 0.f;
          o.z = (v[2] - mu) * rs * g.z + bb.z; o.z = o.z > 0.f ? o.z : 0.f;
          o.w = (v[3] - mu) * rs * g.w + bb.w; o.w = o.w > 0.f ? o.w : 0.f;
          *(float4*)(op + j) = o;
        }
      }
    }
  }
}

// ---------------- launch ----------------------------------------------------
extern "C" void kernel_launch(void* const* d_in, const int* in_sizes, int n_in,
                              void* d_out, int out_size, void* d_ws, size_t ws_size,
                              hipStream_t stream) {
  (void)in_sizes; (void)n_in; (void)out_size; (void)ws_size;
  const float* x       = (const float*)d_in[0];
  const int*   eidx    = (const int*)d_in[1];
  const int*   etype   = (const int*)d_in[2];
  const float* ef      = (const float*)d_in[3];
  const float* W_types = (const float*)d_in[4];
  const float* b_types = (const float*)d_in[5];
  const float* W_self  = (const float*)d_in[6];
  const float* b_self  = (const float*)d_in[7];
  const float* W_e1    = (const float*)d_in[8];
  const float* b_e1    = (const float*)d_in[9];
  const float* W_e2    = (const float*)d_in[10];
  const float* b_e2    = (const float*)d_in[11];
  const float* ln_g    = (const float*)d_in[12];
  const float* ln_b    = (const float*)d_in[13];
  float* out = (float*)d_out;

  char* ws = (char*)d_ws;
  // layout — regions padded well past true size (r3 lesson)
  int*            cnt      = (int*)ws;                    // 25,008 B / 32,768 resv
  int*            bstart   = (int*)(ws + 32768);          // 25,008 / 32,768
  int*            bcur     = (int*)(ws + 65536);          // 25,008 / 32,768
  int*            blocksum = (int*)(ws + 98304);          // 1,024 (256 ints)
  int*            blockoff = (int*)(ws + 99328);          // 1,024
  int*            wq       = (int*)(ws + 100352);         // 4 / pad to 102,400
  int*            rowsorted= (int*)(ws + 102400);         // 2,000,000 B
  unsigned short* xbf      = (unsigned short*)(ws + 2102400);   // 12,800,000 B
  unsigned short* WTt      = (unsigned short*)(ws + 14902400);  // 131,072 B
  unsigned short* W1T      = WTt + 4 * 128 * 128;
  unsigned short* W2T      = W1T + 128 * 128;
  unsigned short* WsT      = W2T + 128 * 128;
  float*          biasc    = (float*)(WsT + 128 * 128);   // 2,048 B

  const int nblk2 = (NBUCK + 255) / 256;  // 25

  hipMemsetAsync(ws, 0, 102400, stream);  // cnt + sums + wq

  prep_kernel<<<25450, 256, 0, stream>>>(x, W_types, b_types, W_self, W_e1, W_e2,
                                         b_e2, xbf, WTt, W1T, W2T, WsT, biasc);
  bhist_kernel<<<512, 256, 0, stream>>>(eidx, etype, cnt);
  scan1_kernel<<<nblk2, 256, 0, stream>>>(cnt, blocksum, NBUCK);
  scan2_kernel<<<1, 256, 0, stream>>>(blocksum, blockoff, nblk2);
  scan3_kernel<<<nblk2, 256, 0, stream>>>(cnt, blockoff, bstart, bcur, NBUCK);
  bscatter_kernel<<<512, 256, 0, stream>>>(eidx, etype, bcur, rowsorted);
  fused_kernel<<<1024, 256, 0, stream>>>(eidx, etype, ef, xbf, WTt, W1T, W2T, WsT,
                                         biasc, b_e1, b_self, ln_g, ln_b,
                                         bstart, rowsorted, wq, out);
}